// Round 5
// baseline (24.265 us; speedup 1.0000x reference)
//
#include <hip/hip_runtime.h>

#define NG    2048
#define IMG_W 128
#define IMG_H 128
#define NPIX  (IMG_W * IMG_H)
#define KCAP  768           // per-tile record capacity (avg ~30, huge headroom)

// ---------------------------------------------------------------------------
// Full fp64 per-gaussian preprocess (identical math/order to rounds 1-3;
// fp64 because radii's ceil() is a discontinuity). Shared by the radii path
// and the per-tile candidate path.
// ---------------------------------------------------------------------------
struct PRec {
    double mx, my, A, B, C, op, z, r2c;
    float radii;
};

__device__ __forceinline__ void preprocess_g(
    int i,
    const float* __restrict__ means, const float* __restrict__ opac,
    const float* __restrict__ scales, const float* __restrict__ rots,
    const float* __restrict__ vm4, PRec& o)
{
    const double fx = 128.0, fy = 128.0;   // W/(2*tanfovx), H/(2*tanfovy)

    double R00 = vm4[0], R01 = vm4[1], R02 = vm4[2],  t0 = vm4[3];
    double R10 = vm4[4], R11 = vm4[5], R12 = vm4[6],  t1 = vm4[7];
    double R20 = vm4[8], R21 = vm4[9], R22 = vm4[10], t2 = vm4[11];

    double m0 = means[3*i+0], m1 = means[3*i+1], m2 = means[3*i+2];
    double x = R00*m0 + R01*m1 + R02*m2 + t0;
    double y = R10*m0 + R11*m1 + R12*m2 + t1;
    double z = R20*m0 + R21*m1 + R22*m2 + t2;

    double zc   = fmax(z, 1e-4);
    double invz = 1.0 / zc;
    const double limx = 1.3 * 0.5, limy = 1.3 * 0.5;
    double tx = fmin(limx, fmax(-limx, x * invz)) * zc;
    double ty = fmin(limy, fmax(-limy, y * invz)) * zc;

    double J00 = fx * invz, J02 = -fx * tx * invz * invz;
    double J11 = fy * invz, J12 = -fy * ty * invz * invz;

    double qw = rots[4*i+0], qx = rots[4*i+1], qy = rots[4*i+2], qz = rots[4*i+3];
    double qn = 1.0 / sqrt(qw*qw + qx*qx + qy*qy + qz*qz);
    qw *= qn; qx *= qn; qy *= qn; qz *= qn;

    double Rg00 = 1.0 - 2.0*(qy*qy + qz*qz), Rg01 = 2.0*(qx*qy - qw*qz), Rg02 = 2.0*(qx*qz + qw*qy);
    double Rg10 = 2.0*(qx*qy + qw*qz), Rg11 = 1.0 - 2.0*(qx*qx + qz*qz), Rg12 = 2.0*(qy*qz - qw*qx);
    double Rg20 = 2.0*(qx*qz - qw*qy), Rg21 = 2.0*(qy*qz + qw*qx), Rg22 = 1.0 - 2.0*(qx*qx + qy*qy);

    double s0 = scales[3*i+0], s1 = scales[3*i+1], s2 = scales[3*i+2]; // SCALE_MOD = 1
    double M00 = Rg00*s0, M01 = Rg01*s1, M02 = Rg02*s2;
    double M10 = Rg10*s0, M11 = Rg11*s1, M12 = Rg12*s2;
    double M20 = Rg20*s0, M21 = Rg21*s1, M22 = Rg22*s2;

    double S00 = M00*M00 + M01*M01 + M02*M02;
    double S01 = M00*M10 + M01*M11 + M02*M12;
    double S02 = M00*M20 + M01*M21 + M02*M22;
    double S11 = M10*M10 + M11*M11 + M12*M12;
    double S12 = M10*M20 + M11*M21 + M12*M22;
    double S22 = M20*M20 + M21*M21 + M22*M22;

    double Ta0 = J00*R00 + J02*R20, Ta1 = J00*R01 + J02*R21, Ta2 = J00*R02 + J02*R22;
    double Tb0 = J11*R10 + J12*R20, Tb1 = J11*R11 + J12*R21, Tb2 = J11*R12 + J12*R22;

    double Ua0 = Ta0*S00 + Ta1*S01 + Ta2*S02;
    double Ua1 = Ta0*S01 + Ta1*S11 + Ta2*S12;
    double Ua2 = Ta0*S02 + Ta1*S12 + Ta2*S22;
    double Ub0 = Tb0*S00 + Tb1*S01 + Tb2*S02;
    double Ub1 = Tb0*S01 + Tb1*S11 + Tb2*S12;
    double Ub2 = Tb0*S02 + Tb1*S12 + Tb2*S22;
    double cov00 = Ua0*Ta0 + Ua1*Ta1 + Ua2*Ta2;
    double cov01 = Ua0*Tb0 + Ua1*Tb1 + Ua2*Tb2;
    double cov11 = Ub0*Tb0 + Ub1*Tb1 + Ub2*Tb2;

    double a = cov00 + 0.3;
    double b = cov01;
    double c = cov11 + 0.3;
    double det = a*c - b*b;
    bool valid = (det > 0.0) && (z > 0.2);
    double inv_det = (det != 0.0) ? (1.0 / det) : 0.0;
    double mid = 0.5 * (a + c);
    double lam = mid + sqrt(fmax(mid*mid - det, 0.1));

    double op = valid ? (double)opac[i] : 0.0;
    double r2c = -1.0;
    if (op > 0.0) {
        double lnterm = log(255.0 * op);
        if (lnterm > 0.0) r2c = 2.0 * lnterm * lam * 1.0001 + 1e-3;
    }

    o.mx  = fx * (x * invz) + 0.5 * (IMG_W - 1);
    o.my  = fy * (y * invz) + 0.5 * (IMG_H - 1);
    o.A   =  c * inv_det;
    o.B   = -b * inv_det;
    o.C   =  a * inv_det;
    o.op  = op;
    o.z   = z;
    o.r2c = r2c;
    o.radii = valid ? (float)ceil(3.0 * sqrt(lam)) : 0.0f;
}

// ---------------------------------------------------------------------------
// ONE kernel: block = one 8x8 tile (256 blocks x 256 threads).
//  P1 cheap fp32 conservative prefilter of all 2048 gaussians
//     (lam_ub = smax^2*||T2||_F^2 + slack  >=  reference lam incl. clamp)
//  P2 radii side-duty: block b fp64-preprocesses gaussians [8b,8b+8)
//  P3 fp64 preprocess of candidates + exact r2cull tile test -> LDS records
//  P4 local stable rank by (z, idx)  == jnp.argsort order on the subset
//  P5 4-wave depth-segment compositing (exact segment combination)
// All contributing-gaussian arithmetic identical to round-3 => same absmax.
// ---------------------------------------------------------------------------
__global__ __launch_bounds__(256) void fused_raster_kernel(
    const float* __restrict__ means,
    const float* __restrict__ opac,
    const float* __restrict__ cols,
    const float* __restrict__ scales,
    const float* __restrict__ rots,
    const float* __restrict__ vm4,
    const float* __restrict__ bg,
    float* __restrict__ out)
{
    __shared__ unsigned short cand[NG];
    __shared__ float recs[KCAP][10];   // mx,my,A,B,C,op,z,r,g,b
    __shared__ float pz[KCAP];
    __shared__ unsigned short pid[KCAP];
    __shared__ unsigned short perm[KCAP];
    __shared__ float comb[4 * 64 * 5];
    __shared__ int cntM, cntK;

    int tid  = threadIdx.x;
    int tile = blockIdx.x;
    int x0 = (tile & 15) * 8;
    int y0 = (tile >> 4) * 8;
    float x0f = (float)x0,       y0f = (float)y0;
    float x1f = (float)(x0 + 7), y1f = (float)(y0 + 7);

    if (tid == 0) { cntM = 0; cntK = 0; }
    __syncthreads();

    // fp32 view rows for the prefilter
    float fR00 = vm4[0], fR01 = vm4[1], fR02 = vm4[2],  ft0 = vm4[3];
    float fR10 = vm4[4], fR11 = vm4[5], fR12 = vm4[6],  ft1 = vm4[7];
    float fR20 = vm4[8], fR21 = vm4[9], fR22 = vm4[10], ft2 = vm4[11];

    // ---- P1: conservative prefilter (8 gaussians/thread) ----
    for (int g = tid; g < NG; g += 256) {
        float m0 = means[3*g+0], m1 = means[3*g+1], m2 = means[3*g+2];
        float x = fR00*m0 + fR01*m1 + fR02*m2 + ft0;
        float y = fR10*m0 + fR11*m1 + fR12*m2 + ft1;
        float z = fR20*m0 + fR21*m1 + fR22*m2 + ft2;
        float zc = fmaxf(z, 1e-4f);
        float invz = 1.0f / zc;
        float xi = x * invz, yi = y * invz;
        float mx = 128.f * xi + 63.5f;
        float my = 128.f * yi + 63.5f;
        float txc = fminf(0.65f, fmaxf(-0.65f, xi));
        float tyc = fminf(0.65f, fmaxf(-0.65f, yi));
        float J00 = 128.f * invz;
        float J02 = -128.f * txc * invz;   // -fx*tx/zc^2 with tx=txc*zc
        float J12 = -128.f * tyc * invz;
        float Ta0 = J00*fR00 + J02*fR20, Ta1 = J00*fR01 + J02*fR21, Ta2 = J00*fR02 + J02*fR22;
        float Tb0 = J00*fR10 + J12*fR20, Tb1 = J00*fR11 + J12*fR21, Tb2 = J00*fR12 + J12*fR22;
        float fro = Ta0*Ta0 + Ta1*Ta1 + Ta2*Ta2 + Tb0*Tb0 + Tb1*Tb1 + Tb2*Tb2;
        float s0 = scales[3*g+0], s1 = scales[3*g+1], s2 = scales[3*g+2];
        float smax2 = fmaxf(s0*s0, fmaxf(s1*s1, s2*s2));
        float op = opac[g];
        float lnterm = __logf(255.f * op);
        bool maybe = false;
        if (lnterm > 0.f) {
            // lam_ref <= tr(cov2d)+0.6+sqrt(0.1)-slack <= fro*smax2+0.92;
            // inflate 2% + 1 px^2 to cover every fp32 rounding path
            float lam_pf = fro * smax2 * 1.02f + 0.95f;
            float r2 = 2.f * lnterm * lam_pf * 1.02f + 1.0f;
            float ddx = fmaxf(0.f, fmaxf(x0f - mx, mx - x1f));
            float ddy = fmaxf(0.f, fmaxf(y0f - my, my - y1f));
            maybe = (ddx*ddx + ddy*ddy) <= r2;
        }
        if (maybe) {
            int s = atomicAdd(&cntM, 1);
            cand[s] = (unsigned short)g;
        }
    }

    // ---- P2: radii side-duty (disjoint across blocks; no barrier needed) ----
    if (tid < 8) {
        int i = tile * 8 + tid;
        PRec o;
        preprocess_g(i, means, opac, scales, rots, vm4, o);
        out[3*NPIX + i] = o.radii;
    }
    __syncthreads();
    int M = cntM;

    // ---- P3: exact fp64 preprocess of candidates + exact tile cull ----
    for (int k = tid; k < M; k += 256) {
        int gi = cand[k];
        PRec o;
        preprocess_g(gi, means, opac, scales, rots, vm4, o);
        float fmx = (float)o.mx, fmy = (float)o.my, fr2 = (float)o.r2c;
        float ddx = fmaxf(0.f, fmaxf(x0f - fmx, fmx - x1f));
        float ddy = fmaxf(0.f, fmaxf(y0f - fmy, fmy - y1f));
        if (ddx*ddx + ddy*ddy <= fr2) {
            int s = atomicAdd(&cntK, 1);
            if (s < KCAP) {
                recs[s][0] = fmx;
                recs[s][1] = fmy;
                recs[s][2] = (float)o.A;
                recs[s][3] = (float)o.B;
                recs[s][4] = (float)o.C;
                recs[s][5] = (float)o.op;
                recs[s][6] = (float)o.z;
                recs[s][7] = cols[3*gi+0];
                recs[s][8] = cols[3*gi+1];
                recs[s][9] = cols[3*gi+2];
                pz[s]  = (float)o.z;
                pid[s] = (unsigned short)gi;
            }
        }
    }
    __syncthreads();
    int K = min(cntK, KCAP);

    // ---- P4: exact stable rank among the K records (z asc, idx asc) ----
    for (int r = tid; r < K; r += 256) {
        float zr = pz[r];
        int ir = pid[r];
        int rank = 0;
        for (int s2 = 0; s2 < K; ++s2)
            rank += (pz[s2] < zr) || (pz[s2] == zr && pid[s2] < ir);
        perm[rank] = (unsigned short)r;
    }
    __syncthreads();

    // ---- P5: 4-wave depth-segment compositing ----
    int lane = tid & 63;
    int w    = tid >> 6;
    int px = x0 + (lane & 7);
    int py = y0 + (lane >> 3);
    float fpx = (float)px, fpy = (float)py;
    int p = py * IMG_W + px;

    int q = (K + 3) >> 2;               // segment length per wave
    int rs = w * q;
    int re = min(rs + q, K);

    float cr = 0.f, cg = 0.f, cb = 0.f, dep = 0.f, T = 1.f;
    for (int r = rs; r < re; ++r) {
        int j = perm[r];                 // uniform per wave -> broadcast reads
        float mx = recs[j][0];
        float my = recs[j][1];
        float A  = recs[j][2];
        float B  = recs[j][3];
        float C  = recs[j][4];
        float op = recs[j][5];
        float dx = mx - fpx;
        float dy = my - fpy;
        float power = -0.5f * (A*dx*dx + C*dy*dy) - B*dx*dy;
        float al = fminf(0.99f, op * __expf(power));
        bool take = (power <= 0.0f) && (al >= (1.0f / 255.0f));
        float wgt = take ? al * T : 0.0f;
        dep += wgt * recs[j][6];
        cr  += wgt * recs[j][7];
        cg  += wgt * recs[j][8];
        cb  += wgt * recs[j][9];
        if (take) T *= (1.0f - al);
    }

    int cb_base = (w * 64 + lane) * 5;
    comb[cb_base + 0] = cr;
    comb[cb_base + 1] = cg;
    comb[cb_base + 2] = cb;
    comb[cb_base + 3] = dep;
    comb[cb_base + 4] = T;
    __syncthreads();

    if (w == 0) {
        float CR = 0.f, CG = 0.f, CB = 0.f, DEP = 0.f, TT = 1.f;
        #pragma unroll
        for (int ww = 0; ww < 4; ++ww) {
            int b2 = (ww * 64 + lane) * 5;
            CR  += TT * comb[b2 + 0];
            CG  += TT * comb[b2 + 1];
            CB  += TT * comb[b2 + 2];
            DEP += TT * comb[b2 + 3];
            TT  *= comb[b2 + 4];
        }
        out[0*NPIX + p] = CR + TT * bg[0];
        out[1*NPIX + p] = CG + TT * bg[1];
        out[2*NPIX + p] = CB + TT * bg[2];
        out[3*NPIX + NG + p]        = DEP;        // depth
        out[3*NPIX + NG + NPIX + p] = 1.f - TT;   // alpha image
    }
}

extern "C" void kernel_launch(void* const* d_in, const int* in_sizes, int n_in,
                              void* d_out, int out_size, void* d_ws, size_t ws_size,
                              hipStream_t stream)
{
    const float* means = (const float*)d_in[0];
    const float* opac  = (const float*)d_in[1];
    const float* cols  = (const float*)d_in[2];
    const float* scl   = (const float*)d_in[3];
    const float* rot   = (const float*)d_in[4];
    const float* vm    = (const float*)d_in[5];
    const float* bg    = (const float*)d_in[6];
    float* out = (float*)d_out;

    fused_raster_kernel<<<256, 256, 0, stream>>>(
        means, opac, cols, scl, rot, vm, bg, out);
}

// Round 6
// 23.800 us; speedup vs baseline: 1.0195x; 1.0195x over previous
//
#include <hip/hip_runtime.h>

#define NG    2048
#define IMG_W 128
#define IMG_H 128
#define NPIX  (IMG_W * IMG_H)
#define KCAP  768           // per-tile record capacity (observed K ~45)

// ---------------------------------------------------------------------------
// ONE kernel, block = one 8x8 tile (256 blocks x 256 threads, 1 block/CU).
//  P1 (waves 1-3): cheap fp32 conservative prefilter of all 2048 gaussians
//      using ||J R||_F^2 <= ||J||_F^2 * ||R||_1 ||R||_inf  (no J*R product)
//  P2 (wave 0, lanes 0-7, CONCURRENT with P1): radii-only fp64 chain for the
//      block's 8 owned gaussians (ceil() discontinuity -> fp64; no div/log)
//  P3: fp32 exact preprocess of candidates + conservative r2cull tile test
//      (fp32 is safe: power<=0 gate is cancellation-robust, al>=1/255 gate
//       flips cost only ~0.004 = observed absmax level; margins inflated)
//  P4: local stable rank by (z_from_fp64, idx) == jnp.argsort on the subset
//  P5: 4-wave depth-segment compositing, exact segment combination
// ---------------------------------------------------------------------------
__global__ __launch_bounds__(256) void fused_raster_kernel(
    const float* __restrict__ means,
    const float* __restrict__ opac,
    const float* __restrict__ cols,
    const float* __restrict__ scales,
    const float* __restrict__ rots,
    const float* __restrict__ vm4,
    const float* __restrict__ bg,
    float* __restrict__ out)
{
    __shared__ unsigned short cand[NG];
    __shared__ float recs[KCAP][10];   // mx,my,A,B,C,op,z,r,g,b
    __shared__ float pz[KCAP];
    __shared__ unsigned short pid[KCAP];
    __shared__ unsigned short perm[KCAP];
    __shared__ float comb[4 * 64 * 5];
    __shared__ int cntM, cntK;

    int tid  = threadIdx.x;
    int tile = blockIdx.x;
    int x0 = (tile & 15) * 8;
    int y0 = (tile >> 4) * 8;
    float x0f = (float)x0,       y0f = (float)y0;
    float x1f = (float)(x0 + 7), y1f = (float)(y0 + 7);

    if (tid == 0) { cntM = 0; cntK = 0; }
    __syncthreads();

    // fp32 view rows (used by P1 and P3)
    float fR00 = vm4[0], fR01 = vm4[1], fR02 = vm4[2],  ft0 = vm4[3];
    float fR10 = vm4[4], fR11 = vm4[5], fR12 = vm4[6],  ft1 = vm4[7];
    float fR20 = vm4[8], fR21 = vm4[9], fR22 = vm4[10], ft2 = vm4[11];

    if (tid >= 64) {
        // ---- P1: conservative prefilter on waves 1-3 (192 threads) ----
        // ||R||_2^2 <= ||R||_1 * ||R||_inf  (Schur bound; =1 for identity)
        float r0s = fabsf(fR00) + fabsf(fR01) + fabsf(fR02);
        float r1s = fabsf(fR10) + fabsf(fR11) + fabsf(fR12);
        float r2s = fabsf(fR20) + fabsf(fR21) + fabsf(fR22);
        float c0s = fabsf(fR00) + fabsf(fR10) + fabsf(fR20);
        float c1s = fabsf(fR01) + fabsf(fR11) + fabsf(fR21);
        float c2s = fabsf(fR02) + fabsf(fR12) + fabsf(fR22);
        float r2norm = fmaxf(r0s, fmaxf(r1s, r2s)) * fmaxf(c0s, fmaxf(c1s, c2s));

        for (int g = tid - 64; g < NG; g += 192) {
            float m0 = means[3*g+0], m1 = means[3*g+1], m2 = means[3*g+2];
            float x = fR00*m0 + fR01*m1 + fR02*m2 + ft0;
            float y = fR10*m0 + fR11*m1 + fR12*m2 + ft1;
            float z = fR20*m0 + fR21*m1 + fR22*m2 + ft2;
            float zc = fmaxf(z, 1e-4f);
            float invz = 1.0f / zc;
            float xi = x * invz, yi = y * invz;
            float mx = 128.f * xi + 63.5f;
            float my = 128.f * yi + 63.5f;
            float txc = fminf(0.65f, fmaxf(-0.65f, xi));
            float tyc = fminf(0.65f, fmaxf(-0.65f, yi));
            float jf = 128.f * invz;
            float frJ = jf * jf * (2.f + txc*txc + tyc*tyc);   // ||J||_F^2
            float s0 = scales[3*g+0], s1 = scales[3*g+1], s2 = scales[3*g+2];
            float smax2 = fmaxf(s0*s0, fmaxf(s1*s1, s2*s2));
            float lnterm = __logf(255.f * opac[g]);
            bool maybe = false;
            if (lnterm > 0.f) {
                // lam_ref <= tr(cov2d)+0.6+sqrt(0.1) <= frJ*r2norm*smax2+0.917
                float lam_pf = frJ * r2norm * smax2 * 1.02f + 0.95f;
                float r2 = 2.f * lnterm * lam_pf * 1.02f + 1.0f;
                float ddx = fmaxf(0.f, fmaxf(x0f - mx, mx - x1f));
                float ddy = fmaxf(0.f, fmaxf(y0f - my, my - y1f));
                maybe = (ddx*ddx + ddy*ddy) <= r2;
            }
            if (maybe) {
                int s = atomicAdd(&cntM, 1);
                cand[s] = (unsigned short)g;
            }
        }
    } else if (tid < 8) {
        // ---- P2: radii-only fp64 chain, 8 owned gaussians (concurrent) ----
        int i = tile * 8 + tid;
        double R00 = vm4[0], R01 = vm4[1], R02 = vm4[2];
        double R10 = vm4[4], R11 = vm4[5], R12 = vm4[6];
        double R20 = vm4[8], R21 = vm4[9], R22 = vm4[10];
        double t2d = vm4[11];
        double m0 = means[3*i+0], m1 = means[3*i+1], m2 = means[3*i+2];
        double x = R00*m0 + R01*m1 + R02*m2 + (double)vm4[3];
        double y = R10*m0 + R11*m1 + R12*m2 + (double)vm4[7];
        double z = R20*m0 + R21*m1 + R22*m2 + t2d;
        double zc   = fmax(z, 1e-4);
        double invz = 1.0 / zc;
        double tx = fmin(0.65, fmax(-0.65, x * invz)) * zc;
        double ty = fmin(0.65, fmax(-0.65, y * invz)) * zc;
        double J00 = 128.0 * invz, J02 = -128.0 * tx * invz * invz;
        double J11 = 128.0 * invz, J12 = -128.0 * ty * invz * invz;
        double qw = rots[4*i+0], qx = rots[4*i+1], qy = rots[4*i+2], qz = rots[4*i+3];
        double qn = 1.0 / sqrt(qw*qw + qx*qx + qy*qy + qz*qz);
        qw *= qn; qx *= qn; qy *= qn; qz *= qn;
        double Rg00 = 1.0-2.0*(qy*qy+qz*qz), Rg01 = 2.0*(qx*qy-qw*qz), Rg02 = 2.0*(qx*qz+qw*qy);
        double Rg10 = 2.0*(qx*qy+qw*qz), Rg11 = 1.0-2.0*(qx*qx+qz*qz), Rg12 = 2.0*(qy*qz-qw*qx);
        double Rg20 = 2.0*(qx*qz-qw*qy), Rg21 = 2.0*(qy*qz+qw*qx), Rg22 = 1.0-2.0*(qx*qx+qy*qy);
        double s0 = scales[3*i+0], s1 = scales[3*i+1], s2 = scales[3*i+2];
        double M00 = Rg00*s0, M01 = Rg01*s1, M02 = Rg02*s2;
        double M10 = Rg10*s0, M11 = Rg11*s1, M12 = Rg12*s2;
        double M20 = Rg20*s0, M21 = Rg21*s1, M22 = Rg22*s2;
        double S00 = M00*M00+M01*M01+M02*M02;
        double S01 = M00*M10+M01*M11+M02*M12;
        double S02 = M00*M20+M01*M21+M02*M22;
        double S11 = M10*M10+M11*M11+M12*M12;
        double S12 = M10*M20+M11*M21+M12*M22;
        double S22 = M20*M20+M21*M21+M22*M22;
        double Ta0 = J00*R00+J02*R20, Ta1 = J00*R01+J02*R21, Ta2 = J00*R02+J02*R22;
        double Tb0 = J11*R10+J12*R20, Tb1 = J11*R11+J12*R21, Tb2 = J11*R12+J12*R22;
        double Ua0 = Ta0*S00+Ta1*S01+Ta2*S02;
        double Ua1 = Ta0*S01+Ta1*S11+Ta2*S12;
        double Ua2 = Ta0*S02+Ta1*S12+Ta2*S22;
        double Ub0 = Tb0*S00+Tb1*S01+Tb2*S02;
        double Ub1 = Tb0*S01+Tb1*S11+Tb2*S12;
        double Ub2 = Tb0*S02+Tb1*S12+Tb2*S22;
        double a = Ua0*Ta0+Ua1*Ta1+Ua2*Ta2 + 0.3;
        double b = Ua0*Tb0+Ua1*Tb1+Ua2*Tb2;
        double c = Ub0*Tb0+Ub1*Tb1+Ub2*Tb2 + 0.3;
        double det = a*c - b*b;
        bool valid = (det > 0.0) && (z > 0.2);
        double mid = 0.5 * (a + c);
        double lam = mid + sqrt(fmax(mid*mid - det, 0.1));
        out[3*NPIX + i] = valid ? (float)ceil(3.0 * sqrt(lam)) : 0.0f;
    }
    __syncthreads();
    int M = cntM;

    // ---- P3: fp32 exact preprocess of candidates + exact-margin tile cull --
    for (int k = tid; k < M; k += 256) {
        int gi = cand[k];
        float m0 = means[3*gi+0], m1 = means[3*gi+1], m2 = means[3*gi+2];
        // fp64 z only for the sort key / depth (3 FMAs; preserves proven order)
        double zd = (double)vm4[8]*m0 + (double)vm4[9]*m1 + (double)vm4[10]*m2 + (double)vm4[11];
        float z = (float)zd;
        float x = fR00*m0 + fR01*m1 + fR02*m2 + ft0;
        float y = fR10*m0 + fR11*m1 + fR12*m2 + ft1;
        float zc = fmaxf(z, 1e-4f);
        float invz = 1.0f / zc;
        float tx = fminf(0.65f, fmaxf(-0.65f, x * invz)) * zc;
        float ty = fminf(0.65f, fmaxf(-0.65f, y * invz)) * zc;
        float J00 = 128.f * invz, J02 = -128.f * tx * invz * invz;
        float J11 = 128.f * invz, J12 = -128.f * ty * invz * invz;
        float qw = rots[4*gi+0], qx = rots[4*gi+1], qy = rots[4*gi+2], qz = rots[4*gi+3];
        float qn = 1.0f / sqrtf(qw*qw + qx*qx + qy*qy + qz*qz);
        qw *= qn; qx *= qn; qy *= qn; qz *= qn;
        float Rg00 = 1.f-2.f*(qy*qy+qz*qz), Rg01 = 2.f*(qx*qy-qw*qz), Rg02 = 2.f*(qx*qz+qw*qy);
        float Rg10 = 2.f*(qx*qy+qw*qz), Rg11 = 1.f-2.f*(qx*qx+qz*qz), Rg12 = 2.f*(qy*qz-qw*qx);
        float Rg20 = 2.f*(qx*qz-qw*qy), Rg21 = 2.f*(qy*qz+qw*qx), Rg22 = 1.f-2.f*(qx*qx+qy*qy);
        float s0 = scales[3*gi+0], s1 = scales[3*gi+1], s2 = scales[3*gi+2];
        float M00 = Rg00*s0, M01 = Rg01*s1, M02 = Rg02*s2;
        float M10 = Rg10*s0, M11 = Rg11*s1, M12 = Rg12*s2;
        float M20 = Rg20*s0, M21 = Rg21*s1, M22 = Rg22*s2;
        float S00 = M00*M00+M01*M01+M02*M02;
        float S01 = M00*M10+M01*M11+M02*M12;
        float S02 = M00*M20+M01*M21+M02*M22;
        float S11 = M10*M10+M11*M11+M12*M12;
        float S12 = M10*M20+M11*M21+M12*M22;
        float S22 = M20*M20+M21*M21+M22*M22;
        float Ta0 = J00*fR00+J02*fR20, Ta1 = J00*fR01+J02*fR21, Ta2 = J00*fR02+J02*fR22;
        float Tb0 = J11*fR10+J12*fR20, Tb1 = J11*fR11+J12*fR21, Tb2 = J11*fR12+J12*fR22;
        float Ua0 = Ta0*S00+Ta1*S01+Ta2*S02;
        float Ua1 = Ta0*S01+Ta1*S11+Ta2*S12;
        float Ua2 = Ta0*S02+Ta1*S12+Ta2*S22;
        float Ub0 = Tb0*S00+Tb1*S01+Tb2*S02;
        float Ub1 = Tb0*S01+Tb1*S11+Tb2*S12;
        float Ub2 = Tb0*S02+Tb1*S12+Tb2*S22;
        float a = Ua0*Ta0+Ua1*Ta1+Ua2*Ta2 + 0.3f;
        float b = Ua0*Tb0+Ua1*Tb1+Ua2*Tb2;
        float c = Ub0*Tb0+Ub1*Tb1+Ub2*Tb2 + 0.3f;
        float det = a*c - b*b;
        bool valid = (det > 0.0f) && (z > 0.2f);
        float inv_det = (det != 0.0f) ? (1.0f / det) : 0.0f;
        float mid = 0.5f * (a + c);
        float lam = mid + sqrtf(fmaxf(mid*mid - det, 0.1f));
        float op = valid ? opac[gi] : 0.0f;
        float r2c = -1.0f;
        if (op > 0.0f) {
            float lnterm = __logf(255.f * op);
            if (lnterm > 0.0f) r2c = 2.f * lnterm * lam * 1.001f + 1e-2f;
        }
        float fmx = 128.f * (x * invz) + 63.5f;
        float fmy = 128.f * (y * invz) + 63.5f;
        float ddx = fmaxf(0.f, fmaxf(x0f - fmx, fmx - x1f));
        float ddy = fmaxf(0.f, fmaxf(y0f - fmy, fmy - y1f));
        if (ddx*ddx + ddy*ddy <= r2c) {
            int s = atomicAdd(&cntK, 1);
            if (s < KCAP) {
                recs[s][0] = fmx;
                recs[s][1] = fmy;
                recs[s][2] =  c * inv_det;
                recs[s][3] = -b * inv_det;
                recs[s][4] =  a * inv_det;
                recs[s][5] = op;
                recs[s][6] = z;
                recs[s][7] = cols[3*gi+0];
                recs[s][8] = cols[3*gi+1];
                recs[s][9] = cols[3*gi+2];
                pz[s]  = z;
                pid[s] = (unsigned short)gi;
            }
        }
    }
    __syncthreads();
    int K = min(cntK, KCAP);

    // ---- P4: exact stable rank among the K records (z asc, idx asc) ----
    for (int r = tid; r < K; r += 256) {
        float zr = pz[r];
        int ir = pid[r];
        int rank = 0;
        for (int s2 = 0; s2 < K; ++s2)
            rank += (pz[s2] < zr) || (pz[s2] == zr && pid[s2] < ir);
        perm[rank] = (unsigned short)r;
    }
    __syncthreads();

    // ---- P5: 4-wave depth-segment compositing ----
    int lane = tid & 63;
    int w    = tid >> 6;
    int px = x0 + (lane & 7);
    int py = y0 + (lane >> 3);
    float fpx = (float)px, fpy = (float)py;
    int p = py * IMG_W + px;

    int q  = (K + 3) >> 2;
    int rs = w * q;
    int re = min(rs + q, K);

    float cr = 0.f, cg = 0.f, cb = 0.f, dep = 0.f, T = 1.f;
    for (int r = rs; r < re; ++r) {
        const float* rr = recs[perm[r]];   // uniform per wave -> broadcast
        float dx = rr[0] - fpx;
        float dy = rr[1] - fpy;
        float power = -0.5f * (rr[2]*dx*dx + rr[4]*dy*dy) - rr[3]*dx*dy;
        float al = fminf(0.99f, rr[5] * __expf(power));
        bool take = (power <= 0.0f) && (al >= (1.0f / 255.0f));
        float wgt = take ? al * T : 0.0f;
        dep += wgt * rr[6];
        cr  += wgt * rr[7];
        cg  += wgt * rr[8];
        cb  += wgt * rr[9];
        if (take) T *= (1.0f - al);
    }

    int cb_base = (w * 64 + lane) * 5;
    comb[cb_base + 0] = cr;
    comb[cb_base + 1] = cg;
    comb[cb_base + 2] = cb;
    comb[cb_base + 3] = dep;
    comb[cb_base + 4] = T;
    __syncthreads();

    if (w == 0) {
        float CR = 0.f, CG = 0.f, CB = 0.f, DEP = 0.f, TT = 1.f;
        #pragma unroll
        for (int ww = 0; ww < 4; ++ww) {
            int b2 = (ww * 64 + lane) * 5;
            CR  += TT * comb[b2 + 0];
            CG  += TT * comb[b2 + 1];
            CB  += TT * comb[b2 + 2];
            DEP += TT * comb[b2 + 3];
            TT  *= comb[b2 + 4];
        }
        out[0*NPIX + p] = CR + TT * bg[0];
        out[1*NPIX + p] = CG + TT * bg[1];
        out[2*NPIX + p] = CB + TT * bg[2];
        out[3*NPIX + NG + p]        = DEP;        // depth
        out[3*NPIX + NG + NPIX + p] = 1.f - TT;   // alpha image
    }
}

extern "C" void kernel_launch(void* const* d_in, const int* in_sizes, int n_in,
                              void* d_out, int out_size, void* d_ws, size_t ws_size,
                              hipStream_t stream)
{
    const float* means = (const float*)d_in[0];
    const float* opac  = (const float*)d_in[1];
    const float* cols  = (const float*)d_in[2];
    const float* scl   = (const float*)d_in[3];
    const float* rot   = (const float*)d_in[4];
    const float* vm    = (const float*)d_in[5];
    const float* bg    = (const float*)d_in[6];
    float* out = (float*)d_out;

    fused_raster_kernel<<<256, 256, 0, stream>>>(
        means, opac, cols, scl, rot, vm, bg, out);
}